// Round 4
// baseline (1931.510 us; speedup 1.0000x reference)
//
#include <hip/hip_runtime.h>

// GC-LSTM (SMPL) — fp32 I/O. Round 4: LDS-bandwidth restructure.
// Kernel 1: 512 blocks x 192 thr, NBATCH=4 (96 rows), whole 48-step recurrence in LDS.
//   Two-pass K GEMM (X,h then in-place A-transform then AX,Ah), 6x8 register tile,
//   d-major weight order so each thread owns all 4 gates -> gate math fused in
//   registers, c-state in registers, G never touches LDS.
// Kernel 2: projection [B*T,576] @ Wd^T + bd; seq staged as bf16 (post-recurrence,
//   additive error only).

#define TPB1 192
#define NBATCH 4

typedef float v2f __attribute__((ext_vector_type(2)));

__device__ __forceinline__ float b2f(unsigned short u) {
    return __uint_as_float(((unsigned int)u) << 16);
}
__device__ __forceinline__ unsigned short f2b(float f) {
    unsigned int x = __float_as_uint(f);
    x = x + 0x7fffu + ((x >> 16) & 1u);   // RNE
    return (unsigned short)(x >> 16);
}
__device__ __forceinline__ float sigm(float x) {
    float t = __expf(-x);
    return 1.0f / (1.0f + t);
}
__device__ __forceinline__ float tanh_(float x) {
    float xc = fmaxf(x, -30.f);
    float t = __expf(-2.f * xc);
    return (1.f - t) / (1.f + t);
}
__device__ __forceinline__ v2f vfma(v2f a, v2f b, v2f c) {
#if __has_builtin(__builtin_elementwise_fma)
    return __builtin_elementwise_fma(a, b, c);
#else
    v2f r; r[0] = fmaf(a[0], b[0], c[0]); r[1] = fmaf(a[1], b[1], c[1]); return r;
#endif
}

// LDS layout (kernel 1), total 55,296 B:
//   UG float[48*96] @ 0     : planes 0-23 X (e), 24-47 h (e); row-major within plane.
//                             In-place becomes AX / Ah between GEMM passes.
//   WL float[2*48*96] @18432: pass-major combined weights, col order n' = d*4+g.
extern "C" __global__ void __launch_bounds__(TPB1)
gclstm_main(const float* __restrict__ src,
            const float* __restrict__ tgt,
            const float* __restrict__ We,
            const float* __restrict__ be,
            const float* __restrict__ Wxl,
            const float* __restrict__ bxl,
            const float* __restrict__ Wxr,
            const float* __restrict__ Whl,
            const float* __restrict__ bhl,
            const float* __restrict__ Whr,
            const float* __restrict__ wg,
            const float* __restrict__ bg,
            unsigned short* __restrict__ seqh)
{
    extern __shared__ char smem[];
    float* UG = (float*)smem;
    float* WL = (float*)(smem + 18432);

    const int tid = threadIdx.x;
    const int b0 = blockIdx.x * NBATCH;
    const int rowg = tid & 15;          // 0..15
    const int colg = tid >> 4;          // 0..11
    const int r0 = rowg * 6;            // rows r0..r0+5
    const int n0 = colg * 8;            // cols n0..n0+7 (d-major: d0,d0+1 x 4 gates)
    const int d0 = colg * 2;

    // ---- pack weights: WL[pass*4608 + k*96 + n'], n' = d*4+g ----
    // pass 0: k=0..23 -> Wxr[e=k], k=24..47 -> Whr[e=k-24]
    // pass 1: k=0..23 -> Wxl,      k=24..47 -> Whl
    for (int i = tid; i < 9216; i += TPB1) {
        int pass = i / 4608, rem = i - pass * 4608;
        int k = rem / 96, np = rem - k * 96;
        int d = np >> 2, g = np & 3;
        int e = k % 24, half = k / 24;
        const float* w = pass == 0 ? (half == 0 ? Wxr : Whr)
                                   : (half == 0 ? Wxl : Whl);
        WL[i] = w[g * 576 + d * 24 + e];
    }

    // ---- per-thread constants ----
    float bias[8], wgi[2], wgf[2], wgo[2];
#pragma unroll
    for (int jj = 0; jj < 8; ++jj) {
        int d = d0 + (jj >> 2), g = jj & 3;
        int n = g * 24 + d;
        bias[jj] = bxl[n] + bhl[n] + bg[n];
    }
#pragma unroll
    for (int dd = 0; dd < 2; ++dd) {
        wgi[dd] = wg[d0 + dd];
        wgf[dd] = wg[24 + d0 + dd];
        wgo[dd] = wg[48 + d0 + dd];
    }

    // ---- per-thread neighbor codes for phase A (24 elems/thread, static) ----
    // ncode: 5-bit slots at bits 0,5,10,15,20 (joint index), count at bits 25-27.
    unsigned int ncode[24];
    {
        const int par[24] = {-1,0,0,0,1,2,3,4,5,6,7,8,9,9,9,12,13,14,16,17,18,19,20,21};
#pragma unroll
        for (int q = 0; q < 24; ++q) {
            int idx = tid + q * TPB1;
            int r = idx % 96;
            int j = r % 24;
            int arr[5] = {0, 0, 0, 0, 0};
            int cnt = 0;
            arr[cnt++] = j;
            if (par[j] >= 0) arr[cnt++] = par[j];
#pragma unroll
            for (int ch = 0; ch < 24; ++ch)
                if (par[ch] == j && cnt < 5) arr[cnt++] = ch;
            ncode[q] = (unsigned int)arr[0] | ((unsigned int)arr[1] << 5)
                     | ((unsigned int)arr[2] << 10) | ((unsigned int)arr[3] << 15)
                     | ((unsigned int)arr[4] << 20) | ((unsigned int)cnt << 25);
        }
    }

    // c-state in registers: thread owns rows r0..r0+5 x d0..d0+1
    float creg[6][2];
#pragma unroll
    for (int i = 0; i < 6; ++i) { creg[i][0] = 0.f; creg[i][1] = 0.f; }

    // ---- encode X0 = relu(enc(src[:,0])); h = 0 ----
#pragma unroll
    for (int q = 0; q < 12; ++q) {
        int idx = tid + q * TPB1;        // idx = d*96 + r over 2304
        int r = idx % 96, d = idx / 96;
        int b = b0 + (r / 24), j = r % 24;
        const float* sp = src + (size_t)b * 1728 + j * 3;
        float x = be[d] + sp[0] * We[d * 3] + sp[1] * We[d * 3 + 1] + sp[2] * We[d * 3 + 2];
        UG[idx] = fmaxf(x, 0.f);         // X plane d
        UG[2304 + idx] = 0.f;            // h plane d
    }
    __syncthreads();

    for (int s = 0; s < 48; ++s) {
        if (s == 24) {
            // decode phase: X = relu(enc(tgt[:,0])), h/c carried
#pragma unroll
            for (int q = 0; q < 12; ++q) {
                int idx = tid + q * TPB1;
                int r = idx % 96, d = idx / 96;
                int b = b0 + (r / 24), j = r % 24;
                const float* tp = tgt + (size_t)b * 1728 + j * 3;
                float x = be[d] + tp[0] * We[d * 3] + tp[1] * We[d * 3 + 1]
                        + tp[2] * We[d * 3 + 2];
                UG[idx] = fmaxf(x, 0.f);
            }
            __syncthreads();
        }

        v2f acc2[3][8];
#pragma unroll
        for (int p = 0; p < 3; ++p)
#pragma unroll
            for (int j = 0; j < 8; ++j) { acc2[p][j][0] = 0.f; acc2[p][j][1] = 0.f; }

        // ---- GEMM pass 1: k over X,h planes; weights Wxr/Whr ----
#pragma unroll 4
        for (int k = 0; k < 48; ++k) {
            const float* up = UG + k * 96 + r0;
            v2f u0 = *(const v2f*)up;
            v2f u1 = *(const v2f*)(up + 2);
            v2f u2 = *(const v2f*)(up + 4);
            const float* wp = WL + k * 96 + n0;
            float4 wa = *(const float4*)wp;
            float4 wb = *(const float4*)(wp + 4);
            float w[8] = {wa.x, wa.y, wa.z, wa.w, wb.x, wb.y, wb.z, wb.w};
#pragma unroll
            for (int j = 0; j < 8; ++j) {
                v2f wv; wv[0] = w[j]; wv[1] = w[j];
                acc2[0][j] = vfma(u0, wv, acc2[0][j]);
                acc2[1][j] = vfma(u1, wv, acc2[1][j]);
                acc2[2][j] = vfma(u2, wv, acc2[2][j]);
            }
        }

        // ---- phase A (stage): read-only gather of A@X, A@h into registers ----
        float ar[24];
#pragma unroll
        for (int q = 0; q < 24; ++q) {
            int idx = tid + q * TPB1;    // idx = t*96 + r over 4608
            int r = idx % 96;
            int j = r % 24;
            const float* P = UG + (idx - j);   // plane t, batch-row base
            unsigned int nc = ncode[q];
            float a = P[nc & 31] + P[(nc >> 5) & 31];
            int c3 = (int)(nc >> 25);
            if (c3 > 2) a += P[(nc >> 10) & 31];
            if (c3 > 3) a += P[(nc >> 15) & 31];
            if (c3 > 4) a += P[(nc >> 20) & 31];
            float iw = (c3 == 2) ? 0.5f : (c3 == 3) ? (1.f / 3.f)
                     : (c3 == 4) ? 0.25f : 0.2f;
            ar[q] = a * iw;
        }
        __syncthreads();   // all pass-1 + stage reads done
#pragma unroll
        for (int q = 0; q < 24; ++q)
            UG[tid + q * TPB1] = ar[q];  // in-place: X->AX, h->Ah
        __syncthreads();

        // ---- GEMM pass 2: k over AX,Ah planes; weights Wxl/Whl ----
#pragma unroll 4
        for (int k = 0; k < 48; ++k) {
            const float* up = UG + k * 96 + r0;
            v2f u0 = *(const v2f*)up;
            v2f u1 = *(const v2f*)(up + 2);
            v2f u2 = *(const v2f*)(up + 4);
            const float* wp = WL + 4608 + k * 96 + n0;
            float4 wa = *(const float4*)wp;
            float4 wb = *(const float4*)(wp + 4);
            float w[8] = {wa.x, wa.y, wa.z, wa.w, wb.x, wb.y, wb.z, wb.w};
#pragma unroll
            for (int j = 0; j < 8; ++j) {
                v2f wv; wv[0] = w[j]; wv[1] = w[j];
                acc2[0][j] = vfma(u0, wv, acc2[0][j]);
                acc2[1][j] = vfma(u1, wv, acc2[1][j]);
                acc2[2][j] = vfma(u2, wv, acc2[2][j]);
            }
        }
        __syncthreads();   // all pass-2 reads done before X/h overwrite

        // ---- fused gate epilogue: all in registers, write next X/h ----
#pragma unroll
        for (int i = 0; i < 6; ++i) {
            float ovv[2];
#pragma unroll
            for (int dd = 0; dd < 2; ++dd) {
                float cold = creg[i][dd];
                float gi = acc2[i >> 1][dd * 4 + 0][i & 1] + bias[dd * 4 + 0];
                float gf = acc2[i >> 1][dd * 4 + 1][i & 1] + bias[dd * 4 + 1];
                float gc = acc2[i >> 1][dd * 4 + 2][i & 1] + bias[dd * 4 + 2];
                float go = acc2[i >> 1][dd * 4 + 3][i & 1] + bias[dd * 4 + 3];
                float iv = sigm(fmaf(wgi[dd], cold, gi));
                float fv = sigm(fmaf(wgf[dd], cold, gf));
                float cn = fmaf(fv, cold, iv * tanh_(gc));
                float ov = sigm(fmaf(wgo[dd], cn, go));
                creg[i][dd] = cn;
                ovv[dd] = ov;
                UG[(d0 + dd) * 96 + r0 + i] = ov;                 // next X
                UG[(24 + d0 + dd) * 96 + r0 + i] = ov * tanh_(cn); // next h
            }
            if (s >= 24) {
                int rr = r0 + i;
                size_t off = ((size_t)(b0 + rr / 24) * 24 + (size_t)(s - 24)) * 576
                           + (size_t)(rr % 24) * 24 + (size_t)d0;
                unsigned int pk = (unsigned int)f2b(ovv[0])
                                | ((unsigned int)f2b(ovv[1]) << 16);
                *(unsigned int*)(seqh + off) = pk;
            }
        }
        __syncthreads();
    }
}

// Kernel 2: out[row][o] = bd[o] + sum_k seq[row][k] * Wd[o][k], rows = B*T = 49152.
// 768 blocks x 192 thr, 64 rows/block, K chunked by 96; seq is bf16.
// LDS: sq float[64*97] @ 0 (24,832 B), wd float[96*72] @ 24832 (27,648 B) => 52,480 B
extern "C" __global__ void __launch_bounds__(192)
gclstm_proj(const unsigned short* __restrict__ seqh,
            const float* __restrict__ Wd,
            const float* __restrict__ bd,
            float* __restrict__ out)
{
    extern __shared__ char smem[];
    float* sq = (float*)smem;
    float* wd = (float*)(smem + 24832);

    const int tid = threadIdx.x;
    const int R0 = blockIdx.x * 64;
    const int rg = tid % 16, cg = tid / 16;   // cg in 0..11
    const int rr = rg * 4, o0 = cg * 6;

    float acc[4][6];
#pragma unroll
    for (int i = 0; i < 4; ++i)
#pragma unroll
        for (int j = 0; j < 6; ++j) acc[i][j] = 0.f;

    for (int k0 = 0; k0 < 576; k0 += 96) {
        __syncthreads();
        for (int i = tid; i < 64 * 48; i += 192) {     // uint = 2 bf16
            int r = i / 48, kp = i - r * 48;
            unsigned int v = *(const unsigned int*)(seqh + (size_t)(R0 + r) * 576
                                                    + (size_t)(k0 + kp * 2));
            sq[r * 97 + kp * 2] = b2f((unsigned short)(v & 0xffffu));
            sq[r * 97 + kp * 2 + 1] = b2f((unsigned short)(v >> 16));
        }
        for (int i = tid; i < 96 * 72; i += 192) {
            int kk = i / 72, o = i - kk * 72;
            wd[kk * 72 + o] = Wd[(size_t)o * 576 + (size_t)(k0 + kk)];
        }
        __syncthreads();
#pragma unroll 4
        for (int kk = 0; kk < 96; ++kk) {
            float ss[4];
#pragma unroll
            for (int i = 0; i < 4; ++i) ss[i] = sq[(rr + i) * 97 + kk];
            const float* wp = wd + kk * 72 + o0;
            float w[6] = {wp[0], wp[1], wp[2], wp[3], wp[4], wp[5]};
#pragma unroll
            for (int i = 0; i < 4; ++i)
#pragma unroll
                for (int j = 0; j < 6; ++j)
                    acc[i][j] = fmaf(ss[i], w[j], acc[i][j]);
        }
    }

#pragma unroll
    for (int j = 0; j < 6; ++j) {
        float bv = bd[o0 + j];
#pragma unroll
        for (int i = 0; i < 4; ++i)
            out[(size_t)(R0 + rr + i) * 72 + (size_t)(o0 + j)] = acc[i][j] + bv;
    }
}

extern "C" void kernel_launch(void* const* d_in, const int* in_sizes, int n_in,
                              void* d_out, int out_size, void* d_ws, size_t ws_size,
                              hipStream_t stream)
{
    const float* src = (const float*)d_in[0];
    const float* tgt = (const float*)d_in[1];
    const float* We  = (const float*)d_in[2];
    const float* be  = (const float*)d_in[3];
    const float* Wxl = (const float*)d_in[4];
    const float* bxl = (const float*)d_in[5];
    const float* Wxr = (const float*)d_in[6];
    const float* Whl = (const float*)d_in[7];
    const float* bhl = (const float*)d_in[8];
    const float* Whr = (const float*)d_in[9];
    const float* wg  = (const float*)d_in[10];
    const float* bg  = (const float*)d_in[11];
    const float* Wd  = (const float*)d_in[12];
    const float* bd  = (const float*)d_in[13];
    float* out = (float*)d_out;                     // [2048][24][72] fp32
    unsigned short* seqh = (unsigned short*)d_ws;   // [2048][24][576] bf16 = 56.6 MB

    gclstm_main<<<dim3(512), dim3(TPB1), 55296, stream>>>(
        src, tgt, We, be, Wxl, bxl, Wxr, Whl, bhl, Whr, wg, bg, seqh);
    gclstm_proj<<<dim3(768), dim3(192), 52480, stream>>>(seqh, Wd, bd, out);
}

// Round 5
// 640.444 us; speedup vs baseline: 3.0159x; 3.0159x over previous
//
#include <hip/hip_runtime.h>

// GC-LSTM (SMPL) — fp32 I/O. Round 5: MFMA restructure.
// Kernel 1: 512 blocks x 256 thr (4 waves), NB=4 batches (96 rows), 48-step
//   recurrence in LDS. Per step: paired elementwise A-transform -> bf16x2-split
//   MFMA GEMM (96x96x96, 16x16x32 tiles, 4 cross terms = ~fp32) -> G overlay
//   with (row+n)%96 swizzle -> fused gate phase (c-state in regs).
// Kernel 2: projection via bf16 MFMA (seq bf16 exact operand, Wd hi/lo split).

typedef short s16x8 __attribute__((ext_vector_type(8)));
typedef float f32x4 __attribute__((ext_vector_type(4)));
typedef int   i32x4 __attribute__((ext_vector_type(4)));

#define TPB 256
#define NB 4
#define US 100            // U/W row stride in dwords (16B-aligned, bank-spread)

__device__ __forceinline__ float b2f(unsigned short u) {
    return __uint_as_float(((unsigned int)u) << 16);
}
__device__ __forceinline__ unsigned short f2b(float f) {
    unsigned int x = __float_as_uint(f);
    x = x + 0x7fffu + ((x >> 16) & 1u);   // RNE
    return (unsigned short)(x >> 16);
}
__device__ __forceinline__ unsigned int packsplit(float x) {
    unsigned short hi = f2b(x);
    float rem = x - b2f(hi);
    unsigned short lo = f2b(rem);
    return ((unsigned int)hi << 16) | (unsigned int)lo;
}
__device__ __forceinline__ float dec(unsigned int u) {
    return __uint_as_float(u & 0xffff0000u) + __uint_as_float(u << 16);
}
__device__ __forceinline__ float sigm(float x) {
    float t = __expf(-x);
    return 1.0f / (1.0f + t);
}
__device__ __forceinline__ float tanh_(float x) {
    float xc = fmaxf(x, -30.f);
    float t = __expf(-2.f * xc);
    return (1.f - t) / (1.f + t);
}
// load 8 packed (hi<<16|lo) u32 from LDS -> hi-frag, lo-frag (8 bf16 each)
__device__ __forceinline__ void ldfrag(const unsigned int* base, s16x8& hi, s16x8& lo) {
    i32x4 ra = *(const i32x4*)(base);
    i32x4 rb = *(const i32x4*)(base + 4);
    union { i32x4 v; s16x8 s; } H, L;
    H.v[0] = (int)((((unsigned)ra[0]) >> 16) | (((unsigned)ra[1]) & 0xffff0000u));
    H.v[1] = (int)((((unsigned)ra[2]) >> 16) | (((unsigned)ra[3]) & 0xffff0000u));
    H.v[2] = (int)((((unsigned)rb[0]) >> 16) | (((unsigned)rb[1]) & 0xffff0000u));
    H.v[3] = (int)((((unsigned)rb[2]) >> 16) | (((unsigned)rb[3]) & 0xffff0000u));
    L.v[0] = (int)((((unsigned)ra[0]) & 0xffffu) | (((unsigned)ra[1]) << 16));
    L.v[1] = (int)((((unsigned)ra[2]) & 0xffffu) | (((unsigned)ra[3]) << 16));
    L.v[2] = (int)((((unsigned)rb[0]) & 0xffffu) | (((unsigned)rb[1]) << 16));
    L.v[3] = (int)((((unsigned)rb[2]) & 0xffffu) | (((unsigned)rb[3]) << 16));
    hi = H.s; lo = L.s;
}

extern "C" __global__ void __launch_bounds__(TPB, 2)
gclstm_main(const float* __restrict__ src,
            const float* __restrict__ tgt,
            const float* __restrict__ We,
            const float* __restrict__ be,
            const float* __restrict__ Wxl,
            const float* __restrict__ bxl,
            const float* __restrict__ Wxr,
            const float* __restrict__ Whl,
            const float* __restrict__ bhl,
            const float* __restrict__ Whr,
            const float* __restrict__ wg,
            const float* __restrict__ bg,
            unsigned short* __restrict__ seqh)
{
    // U: packed u32 [96 rows][US]; k-cols 0-23 AX | 24-47 X | 48-71 Ah | 72-95 h
    // G (fp32 bits in u32) overlays U after GEMM: addr = n*US + (row+n)%96
    __shared__ unsigned int UB[96 * US];      // 38,400 B
    __shared__ unsigned int WB[96 * US];      // 38,400 B  W[n][k] packed hi/lo
    __shared__ float biasL[96];
    __shared__ float wgL[72];

    const int tid = threadIdx.x;
    const int b0 = blockIdx.x * NB;
    const int lane = tid & 63, wid = tid >> 6;
    const int l15 = lane & 15, quad = lane >> 4;
    const int mt0 = (wid >> 1) * 3, nt0 = (wid & 1) * 3;

    // ---- stage weights: WB[n*US + k], n = g*24+d; k: 0-23 Wxl | 24-47 Wxr |
    //      48-71 Whl | 72-95 Whr (pairs with U's k planes) ----
    for (int i = tid; i < 9216; i += TPB) {
        int n = i / 96, k = i - n * 96;
        int g = n / 24, d = n - g * 24;
        int e = k % 24, sel = k / 24;
        const float* w = sel == 0 ? Wxl : sel == 1 ? Wxr : sel == 2 ? Whl : Whr;
        WB[n * US + k] = packsplit(w[g * 576 + d * 24 + e]);
    }
    if (tid < 96) biasL[tid] = bxl[tid] + bhl[tid] + bg[tid];
    if (tid < 72) wgL[tid] = wg[tid];

    // ---- per-thread neighbor codes for A-phase tasks (5 tasks, pad = self) ----
    unsigned int ncode[5];
    {
        const int par[24] = {-1,0,0,0,1,2,3,4,5,6,7,8,9,9,9,12,13,14,16,17,18,19,20,21};
#pragma unroll
        for (int t = 0; t < 5; ++t) {
            int task = tid + t * TPB;
            int row = task % 96;
            int j = row % 24;
            int arr[5];
            int cnt = 0;
            arr[cnt++] = j;
            if (par[j] >= 0) arr[cnt++] = par[j];
#pragma unroll
            for (int ch = 0; ch < 24; ++ch)
                if (par[ch] == j && cnt < 5) arr[cnt++] = ch;
            for (int m = cnt; m < 5; ++m) arr[m] = j;   // pad with self
            ncode[t] = (unsigned int)arr[0] | ((unsigned int)arr[1] << 5)
                     | ((unsigned int)arr[2] << 10) | ((unsigned int)arr[3] << 15)
                     | ((unsigned int)arr[4] << 20) | ((unsigned int)cnt << 25);
        }
    }

    float creg[5][2];
#pragma unroll
    for (int t = 0; t < 5; ++t) { creg[t][0] = 0.f; creg[t][1] = 0.f; }

    // ---- encoder: X0 = relu(enc(src[:,0])); h = 0 ----
#pragma unroll
    for (int t = 0; t < 5; ++t) {
        int task = tid + t * TPB;
        if (task < 1152) {
            int row = task % 96, dp = task / 96;
            int b = b0 + row / 24, j = row % 24;
            const float* sp = src + (size_t)b * 1728 + j * 3;
            float s0 = sp[0], s1 = sp[1], s2 = sp[2];
            int d0 = 2 * dp;
            float x0 = be[d0] + s0 * We[d0 * 3] + s1 * We[d0 * 3 + 1] + s2 * We[d0 * 3 + 2];
            float x1 = be[d0 + 1] + s0 * We[d0 * 3 + 3] + s1 * We[d0 * 3 + 4]
                     + s2 * We[d0 * 3 + 5];
            UB[row * US + 24 + d0] = packsplit(fmaxf(x0, 0.f));
            UB[row * US + 24 + d0 + 1] = packsplit(fmaxf(x1, 0.f));
            UB[row * US + 72 + d0] = 0u;
            UB[row * US + 72 + d0 + 1] = 0u;
        }
    }
    __syncthreads();

    for (int s = 0; s < 48; ++s) {
        if (s == 24) {
            // decode: X = relu(enc(tgt[:,0])), h/c carried
#pragma unroll
            for (int t = 0; t < 5; ++t) {
                int task = tid + t * TPB;
                if (task < 1152) {
                    int row = task % 96, dp = task / 96;
                    int b = b0 + row / 24, j = row % 24;
                    const float* tp = tgt + (size_t)b * 1728 + j * 3;
                    float s0 = tp[0], s1 = tp[1], s2 = tp[2];
                    int d0 = 2 * dp;
                    float x0 = be[d0] + s0 * We[d0 * 3] + s1 * We[d0 * 3 + 1]
                             + s2 * We[d0 * 3 + 2];
                    float x1 = be[d0 + 1] + s0 * We[d0 * 3 + 3] + s1 * We[d0 * 3 + 4]
                             + s2 * We[d0 * 3 + 5];
                    UB[row * US + 24 + d0] = packsplit(fmaxf(x0, 0.f));
                    UB[row * US + 24 + d0 + 1] = packsplit(fmaxf(x1, 0.f));
                }
            }
            __syncthreads();
        }

        // ---- A-phase: AX (cols 0-23) from X (24-47); Ah (48-71) from h (72-95) ----
#pragma unroll
        for (int t = 0; t < 5; ++t) {
            int task = tid + t * TPB;
            if (task < 1152) {
                int row = task % 96, ep = task / 96;
                int rb = row - (row % 24);
                unsigned int nc = ncode[t];
                int cnt = (int)(nc >> 25);
                float sx0 = 0.f, sx1 = 0.f, sh0 = 0.f, sh1 = 0.f;
                float fx0 = 0.f, fx1 = 0.f, fh0 = 0.f, fh1 = 0.f;
#pragma unroll
                for (int m = 0; m < 5; ++m) {
                    int nb = (int)((nc >> (5 * m)) & 31u);
                    const unsigned int* P = &UB[(rb + nb) * US + 24 + 2 * ep];
                    float vx0 = dec(P[0]), vx1 = dec(P[1]);
                    float vh0 = dec(P[48]), vh1 = dec(P[49]);
                    sx0 += vx0; sx1 += vx1; sh0 += vh0; sh1 += vh1;
                    if (m == 0) { fx0 = vx0; fx1 = vx1; fh0 = vh0; fh1 = vh1; }
                }
                float corr = (float)(5 - cnt);
                float iw = cnt == 2 ? 0.5f : cnt == 3 ? (1.f / 3.f)
                         : cnt == 4 ? 0.25f : 0.2f;
                unsigned int* Q = &UB[row * US + 2 * ep];
                Q[0]  = packsplit((sx0 - corr * fx0) * iw);
                Q[1]  = packsplit((sx1 - corr * fx1) * iw);
                Q[48] = packsplit((sh0 - corr * fh0) * iw);
                Q[49] = packsplit((sh1 - corr * fh1) * iw);
            }
        }
        __syncthreads();

        // ---- GEMM: G[row][n] = sum_k U[row][k]*W[n][k], bf16x2 split, 4 terms ----
        f32x4 acc[3][3];
#pragma unroll
        for (int i = 0; i < 3; ++i)
#pragma unroll
            for (int j = 0; j < 3; ++j) acc[i][j] = (f32x4)0.f;

#pragma unroll
        for (int kt = 0; kt < 3; ++kt) {
            int koff = kt * 32 + quad * 8;
            s16x8 ah[3], al[3], bh[3], bl[3];
#pragma unroll
            for (int i = 0; i < 3; ++i) {
                int rowi = (mt0 + i) * 16 + l15;
                ldfrag(&UB[rowi * US + koff], ah[i], al[i]);
                int ni = (nt0 + i) * 16 + l15;
                ldfrag(&WB[ni * US + koff], bh[i], bl[i]);
            }
#pragma unroll
            for (int i = 0; i < 3; ++i)
#pragma unroll
                for (int j = 0; j < 3; ++j) {
                    acc[i][j] = __builtin_amdgcn_mfma_f32_16x16x32_bf16(ah[i], bh[j], acc[i][j], 0, 0, 0);
                    acc[i][j] = __builtin_amdgcn_mfma_f32_16x16x32_bf16(ah[i], bl[j], acc[i][j], 0, 0, 0);
                    acc[i][j] = __builtin_amdgcn_mfma_f32_16x16x32_bf16(al[i], bh[j], acc[i][j], 0, 0, 0);
                    acc[i][j] = __builtin_amdgcn_mfma_f32_16x16x32_bf16(al[i], bl[j], acc[i][j], 0, 0, 0);
                }
        }
        __syncthreads();   // all U reads done before G overlays

        // ---- G-write (+bias): G[n][(row+n)%96] overlaying UB ----
#pragma unroll
        for (int j = 0; j < 3; ++j) {
            int n = (nt0 + j) * 16 + l15;
            float bn = biasL[n];
#pragma unroll
            for (int i = 0; i < 3; ++i) {
                int rbase = (mt0 + i) * 16 + quad * 4;
#pragma unroll
                for (int r = 0; r < 4; ++r) {
                    int row = rbase + r;
                    int rs = row + n; if (rs >= 96) rs -= 96;
                    UB[n * US + rs] = __float_as_uint(acc[i][j][r] + bn);
                }
            }
        }
        __syncthreads();

        // ---- gate phase: read G, compute, stash; write seq ----
        float ovv[5][2], hvv[5][2];
#pragma unroll
        for (int t = 0; t < 5; ++t) {
            int task = tid + t * TPB;
            if (task < 1152) {
                int row = task % 96, dp = task / 96;
#pragma unroll
                for (int dd = 0; dd < 2; ++dd) {
                    int d = 2 * dp + dd;
                    float c = creg[t][dd];
                    int n0 = d, n1 = 24 + d, n2 = 48 + d, n3 = 72 + d;
                    int r0 = row + n0; if (r0 >= 96) r0 -= 96;
                    int r1 = row + n1; if (r1 >= 96) r1 -= 96;
                    int r2 = row + n2; if (r2 >= 96) r2 -= 96;
                    int r3 = row + n3; if (r3 >= 96) r3 -= 96;
                    float gi = __uint_as_float(UB[n0 * US + r0]);
                    float gf = __uint_as_float(UB[n1 * US + r1]);
                    float gc = __uint_as_float(UB[n2 * US + r2]);
                    float go = __uint_as_float(UB[n3 * US + r3]);
                    float iv = sigm(fmaf(wgL[d], c, gi));
                    float fv = sigm(fmaf(wgL[24 + d], c, gf));
                    float cn = fmaf(fv, c, iv * tanh_(gc));
                    float ov = sigm(fmaf(wgL[48 + d], cn, go));
                    creg[t][dd] = cn;
                    ovv[t][dd] = ov;
                    hvv[t][dd] = ov * tanh_(cn);
                }
                if (s >= 24) {
                    size_t off = ((size_t)(b0 + row / 24) * 24 + (size_t)(s - 24)) * 576
                               + (size_t)(row % 24) * 24 + (size_t)(2 * dp);
                    unsigned int pk = (unsigned int)f2b(ovv[t][0])
                                    | ((unsigned int)f2b(ovv[t][1]) << 16);
                    *(unsigned int*)(seqh + off) = pk;
                }
            }
        }
        __syncthreads();   // all G reads done before X/h overwrite

        // ---- write next X (cols 24-47) and h (cols 72-95) ----
#pragma unroll
        for (int t = 0; t < 5; ++t) {
            int task = tid + t * TPB;
            if (task < 1152) {
                int row = task % 96, dp = task / 96;
                unsigned int* Q = &UB[row * US + 24 + 2 * dp];
                Q[0]  = packsplit(ovv[t][0]);
                Q[1]  = packsplit(ovv[t][1]);
                Q[48] = packsplit(hvv[t][0]);
                Q[49] = packsplit(hvv[t][1]);
            }
        }
        __syncthreads();
    }
}

// Kernel 2: out[row][o] = bd[o] + sum_k seq[row][k]*Wd[o][k]; MFMA bf16,
// seq exact bf16 A-operand, Wd split hi/lo. 384 blocks x 256 thr, 128 rows/blk.
extern "C" __global__ void __launch_bounds__(TPB, 2)
gclstm_proj(const unsigned short* __restrict__ seqh,
            const float* __restrict__ Wd,
            const float* __restrict__ bd,
            float* __restrict__ out)
{
    __shared__ unsigned short SQ[128 * 104];   // 26,624 B
    __shared__ unsigned short WH[80 * 104];    // 16,640 B
    __shared__ unsigned short WL[80 * 104];    // 16,640 B

    const int tid = threadIdx.x;
    const int R0 = blockIdx.x * 128;
    const int lane = tid & 63, wid = tid >> 6;
    const int l15 = lane & 15, quad = lane >> 4;

    f32x4 acc[2][5];
#pragma unroll
    for (int i = 0; i < 2; ++i)
#pragma unroll
        for (int j = 0; j < 5; ++j) acc[i][j] = (f32x4)0.f;

    for (int kc = 0; kc < 576; kc += 96) {
        __syncthreads();
        // stage seq tile: 128 rows x 96 k (bf16), 16B chunks
        for (int i = tid; i < 1536; i += TPB) {
            int r = i / 12, c8 = i - r * 12;
            const i32x4* gp = (const i32x4*)(seqh + (size_t)(R0 + r) * 576
                                             + (size_t)(kc + c8 * 8));
            *(i32x4*)(&SQ[r * 104 + c8 * 8]) = *gp;
        }
        // stage Wd split (rows 72-79 zero-padded)
        for (int i = tid; i < 7680; i += TPB) {
            int n = i / 96, kk = i - n * 96;
            float v = (n < 72) ? Wd[(size_t)n * 576 + (size_t)(kc + kk)] : 0.f;
            unsigned short h = f2b(v);
            unsigned short l = f2b(v - b2f(h));
            WH[n * 104 + kk] = h;
            WL[n * 104 + kk] = l;
        }
        __syncthreads();
#pragma unroll
        for (int kt = 0; kt < 3; ++kt) {
            int koff = kt * 32 + quad * 8;
            s16x8 a[2], bh[5], bl[5];
#pragma unroll
            for (int i = 0; i < 2; ++i)
                a[i] = *(const s16x8*)(&SQ[((wid * 2 + i) * 16 + l15) * 104 + koff]);
#pragma unroll
            for (int j = 0; j < 5; ++j) {
                bh[j] = *(const s16x8*)(&WH[(j * 16 + l15) * 104 + koff]);
                bl[j] = *(const s16x8*)(&WL[(j * 16 + l15) * 104 + koff]);
            }
#pragma unroll
            for (int i = 0; i < 2; ++i)
#pragma unroll
                for (int j = 0; j < 5; ++j) {
                    acc[i][j] = __builtin_amdgcn_mfma_f32_16x16x32_bf16(a[i], bh[j], acc[i][j], 0, 0, 0);
                    acc[i][j] = __builtin_amdgcn_mfma_f32_16x16x32_bf16(a[i], bl[j], acc[i][j], 0, 0, 0);
                }
        }
    }

#pragma unroll
    for (int j = 0; j < 5; ++j) {
        int n = j * 16 + l15;
        if (n < 72) {
            float bv = bd[n];
#pragma unroll
            for (int i = 0; i < 2; ++i) {
                int rbase = R0 + (wid * 2 + i) * 16 + quad * 4;
#pragma unroll
                for (int r = 0; r < 4; ++r)
                    out[(size_t)(rbase + r) * 72 + (size_t)n] = acc[i][j][r] + bv;
            }
        }
    }
}

extern "C" void kernel_launch(void* const* d_in, const int* in_sizes, int n_in,
                              void* d_out, int out_size, void* d_ws, size_t ws_size,
                              hipStream_t stream)
{
    const float* src = (const float*)d_in[0];
    const float* tgt = (const float*)d_in[1];
    const float* We  = (const float*)d_in[2];
    const float* be  = (const float*)d_in[3];
    const float* Wxl = (const float*)d_in[4];
    const float* bxl = (const float*)d_in[5];
    const float* Wxr = (const float*)d_in[6];
    const float* Whl = (const float*)d_in[7];
    const float* bhl = (const float*)d_in[8];
    const float* Whr = (const float*)d_in[9];
    const float* wg  = (const float*)d_in[10];
    const float* bg  = (const float*)d_in[11];
    const float* Wd  = (const float*)d_in[12];
    const float* bd  = (const float*)d_in[13];
    float* out = (float*)d_out;                     // [2048][24][72] fp32
    unsigned short* seqh = (unsigned short*)d_ws;   // [2048][24][576] bf16

    gclstm_main<<<dim3(512), dim3(TPB), 0, stream>>>(
        src, tgt, We, be, Wxl, bxl, Wxr, Whl, bhl, Whr, wg, bg, seqh);
    gclstm_proj<<<dim3(384), dim3(TPB), 0, stream>>>(seqh, Wd, bd, out);
}

// Round 6
// 424.523 us; speedup vs baseline: 4.5498x; 1.5086x over previous
//
#include <hip/hip_runtime.h>

// GC-LSTM (SMPL) — fp32 I/O. Round 6: lean elementwise + single-bf16 MFMA.
// Kernel 1: 512 blocks x 256 thr (4 waves), NB=4 (96 rows), 48 steps in LDS.
//   State X,h kept fp32 in XH (stride 50, bank-clean) for the A-gather; MFMA
//   operands bf16 single (no hi/lo split) -> 27 MFMA/wave/step; task map
//   (row,dp) with 12 lanes per row -> consecutive-bank scalar LDS; rcp-based
//   gates. G overlays UO+XH (dead between phases).
// Kernel 2: projection, bf16 MFMA single-term (Wd-hi).

typedef short s16x8 __attribute__((ext_vector_type(8)));
typedef float f32x4 __attribute__((ext_vector_type(4)));

#define TPB 256
#define NB 4
// LDS byte offsets
#define UO_OFF   0        // ushort [96][104] = 19,968 : k 0-23 AX |24-47 X |48-71 Ah |72-95 h
#define XH_OFF   19968    // float  [96][50]  = 19,200 : 0-23 X fp32 | 24-47 h fp32
#define G_OFF    0        // float  [96][100] = 38,400 : overlays UO+XH (phase-dead)
#define W_OFF    39168    // ushort [96][104] = 19,968 : W[n][k] bf16
#define BIAS_OFF 59136    // float[96]
#define WG_OFF   59520    // float[72]
#define SMEM_SZ  59808

__device__ __forceinline__ float b2f(unsigned short u) {
    return __uint_as_float(((unsigned int)u) << 16);
}
__device__ __forceinline__ unsigned short f2b(float f) {
    unsigned int x = __float_as_uint(f);
    x = x + 0x7fffu + ((x >> 16) & 1u);   // RNE
    return (unsigned short)(x >> 16);
}
__device__ __forceinline__ unsigned int pk2(float a, float b) {
    return (unsigned int)f2b(a) | ((unsigned int)f2b(b) << 16);
}
__device__ __forceinline__ float frcp(float x) { return __builtin_amdgcn_rcpf(x); }
__device__ __forceinline__ float sigm(float x) {
    float t = __expf(-x);
    return frcp(1.0f + t);
}
__device__ __forceinline__ float tanh_(float x) {
    float xc = fmaxf(x, -30.f);
    float t = __expf(-2.f * xc);
    return (1.f - t) * frcp(1.f + t);
}

extern "C" __global__ void __launch_bounds__(TPB, 2)
gclstm_main(const float* __restrict__ src,
            const float* __restrict__ tgt,
            const float* __restrict__ We,
            const float* __restrict__ be,
            const float* __restrict__ Wxl,
            const float* __restrict__ bxl,
            const float* __restrict__ Wxr,
            const float* __restrict__ Whl,
            const float* __restrict__ bhl,
            const float* __restrict__ Whr,
            const float* __restrict__ wg,
            const float* __restrict__ bg,
            unsigned short* __restrict__ seqh)
{
    __shared__ __align__(16) char smem[SMEM_SZ];
    unsigned short* UO = (unsigned short*)(smem + UO_OFF);
    float* XH = (float*)(smem + XH_OFF);
    float* G  = (float*)(smem + G_OFF);
    unsigned short* WO = (unsigned short*)(smem + W_OFF);
    float* biasL = (float*)(smem + BIAS_OFF);
    float* wgL = (float*)(smem + WG_OFF);

    const int tid = threadIdx.x;
    const int b0 = blockIdx.x * NB;
    const int lane = tid & 63, wid = tid >> 6;
    const int l15 = lane & 15, quad = lane >> 4;
    const int mt0 = (wid >> 1) * 3, nt0 = (wid & 1) * 3;

    // ---- stage W[n][k] bf16; k pairs U planes: 0-23 Wxl |24-47 Wxr |48-71 Whl |72-95 Whr
    for (int i = tid; i < 9216; i += TPB) {
        int n = i / 96, k = i - n * 96;
        int g = n / 24, d = n - g * 24;
        int e = k % 24, sel = k / 24;
        const float* w = sel == 0 ? Wxl : sel == 1 ? Wxr : sel == 2 ? Whl : Whr;
        WO[n * 104 + k] = f2b(w[g * 576 + d * 24 + e]);
    }
    if (tid < 96) biasL[tid] = bxl[tid] + bhl[tid] + bg[tid];
    if (tid < 72) wgL[tid] = wg[tid];

    // ---- per-thread task constants: task = row*12 + dp (1152 tasks) ----
    int rowT[5], dpT[5], rbT[5];
    unsigned int ncodeT[5];
    long long seqbT[5];
    {
        const int par[24] = {-1,0,0,0,1,2,3,4,5,6,7,8,9,9,9,12,13,14,16,17,18,19,20,21};
#pragma unroll
        for (int t = 0; t < 5; ++t) {
            int task = tid + t * TPB;
            int row = task / 12, dp = task - row * 12;
            if (row > 95) row = 95;                 // clamp (guarded by valid checks)
            int j = row % 24;
            rowT[t] = row; dpT[t] = dp; rbT[t] = row - j;
            int arr[5]; int cnt = 0;
            arr[cnt++] = j;
            if (par[j] >= 0) arr[cnt++] = par[j];
#pragma unroll
            for (int ch = 0; ch < 24; ++ch)
                if (par[ch] == j && cnt < 5) arr[cnt++] = ch;
            for (int m = cnt; m < 5; ++m) arr[m] = j;  // self-pad
            ncodeT[t] = (unsigned int)arr[0] | ((unsigned int)arr[1] << 5)
                      | ((unsigned int)arr[2] << 10) | ((unsigned int)arr[3] << 15)
                      | ((unsigned int)arr[4] << 20) | ((unsigned int)cnt << 25);
            seqbT[t] = (long long)(b0 + row / 24) * 24 * 576 + (long long)j * 24 + 2 * dp;
        }
    }

    float creg[5][2];
#pragma unroll
    for (int t = 0; t < 5; ++t) { creg[t][0] = 0.f; creg[t][1] = 0.f; }

    // ---- encoder init: X0 = relu(enc(src[:,0])), h = 0 ----
#pragma unroll
    for (int t = 0; t < 5; ++t) {
        int task = tid + t * TPB;
        if (task < 1152) {
            int row = rowT[t], dp = dpT[t];
            int b = b0 + row / 24, j = row % 24;
            const float* sp = src + (size_t)b * 1728 + j * 3;
            float s0 = sp[0], s1 = sp[1], s2 = sp[2];
            int d = 2 * dp;
            float x0 = be[d] + s0 * We[d * 3] + s1 * We[d * 3 + 1] + s2 * We[d * 3 + 2];
            float x1 = be[d + 1] + s0 * We[d * 3 + 3] + s1 * We[d * 3 + 4] + s2 * We[d * 3 + 5];
            x0 = fmaxf(x0, 0.f); x1 = fmaxf(x1, 0.f);
            *(unsigned int*)(UO + row * 104 + 24 + d) = pk2(x0, x1);
            *(unsigned int*)(UO + row * 104 + 72 + d) = 0u;
            XH[row * 50 + d] = x0; XH[row * 50 + d + 1] = x1;
            XH[row * 50 + 24 + d] = 0.f; XH[row * 50 + 24 + d + 1] = 0.f;
        }
    }
    __syncthreads();

    for (int s = 0; s < 48; ++s) {
        if (s == 24) {
            // decode inject: X = relu(enc(tgt[:,0]))
#pragma unroll
            for (int t = 0; t < 5; ++t) {
                int task = tid + t * TPB;
                if (task < 1152) {
                    int row = rowT[t], dp = dpT[t];
                    int b = b0 + row / 24, j = row % 24;
                    const float* tp = tgt + (size_t)b * 1728 + j * 3;
                    float s0 = tp[0], s1 = tp[1], s2 = tp[2];
                    int d = 2 * dp;
                    float x0 = be[d] + s0 * We[d * 3] + s1 * We[d * 3 + 1] + s2 * We[d * 3 + 2];
                    float x1 = be[d + 1] + s0 * We[d * 3 + 3] + s1 * We[d * 3 + 4]
                             + s2 * We[d * 3 + 5];
                    x0 = fmaxf(x0, 0.f); x1 = fmaxf(x1, 0.f);
                    *(unsigned int*)(UO + row * 104 + 24 + d) = pk2(x0, x1);
                    XH[row * 50 + d] = x0; XH[row * 50 + d + 1] = x1;
                }
            }
            __syncthreads();
        }

        // ---- A-phase: gather from XH (fp32), write AX,Ah bf16 into UO ----
#pragma unroll
        for (int t = 0; t < 5; ++t) {
            int task = tid + t * TPB;
            if (task < 1152) {
                int row = rowT[t], dp = dpT[t], rb = rbT[t];
                unsigned int nc = ncodeT[t];
                int cnt = (int)(nc >> 25);
                float sx0 = 0.f, sx1 = 0.f, sh0 = 0.f, sh1 = 0.f;
                float fx0 = 0.f, fx1 = 0.f, fh0 = 0.f, fh1 = 0.f;
#pragma unroll
                for (int m = 0; m < 5; ++m) {
                    int nb = (int)((nc >> (5 * m)) & 31u);
                    const float* P = XH + (rb + nb) * 50 + 2 * dp;
                    float vx0 = P[0], vx1 = P[1];
                    float vh0 = P[24], vh1 = P[25];
                    sx0 += vx0; sx1 += vx1; sh0 += vh0; sh1 += vh1;
                    if (m == 0) { fx0 = vx0; fx1 = vx1; fh0 = vh0; fh1 = vh1; }
                }
                float corr = (float)(5 - cnt);
                float iw = cnt == 2 ? 0.5f : cnt == 3 ? (1.f / 3.f)
                         : cnt == 4 ? 0.25f : 0.2f;
                *(unsigned int*)(UO + row * 104 + 2 * dp) =
                    pk2((sx0 - corr * fx0) * iw, (sx1 - corr * fx1) * iw);
                *(unsigned int*)(UO + row * 104 + 48 + 2 * dp) =
                    pk2((sh0 - corr * fh0) * iw, (sh1 - corr * fh1) * iw);
            }
        }
        __syncthreads();

        // ---- GEMM: G[row][n] = sum_k U[row][k]*W[n][k], single bf16 term ----
        f32x4 acc[3][3];
#pragma unroll
        for (int i = 0; i < 3; ++i)
#pragma unroll
            for (int j = 0; j < 3; ++j) acc[i][j] = (f32x4)0.f;
#pragma unroll
        for (int kt = 0; kt < 3; ++kt) {
            int koff = kt * 32 + quad * 8;
            s16x8 a[3], b[3];
#pragma unroll
            for (int i = 0; i < 3; ++i) {
                a[i] = *(const s16x8*)(UO + ((mt0 + i) * 16 + l15) * 104 + koff);
                b[i] = *(const s16x8*)(WO + ((nt0 + i) * 16 + l15) * 104 + koff);
            }
#pragma unroll
            for (int i = 0; i < 3; ++i)
#pragma unroll
                for (int j = 0; j < 3; ++j)
                    acc[i][j] = __builtin_amdgcn_mfma_f32_16x16x32_bf16(a[i], b[j], acc[i][j], 0, 0, 0);
        }
        __syncthreads();   // all UO reads done before G overlay

        // ---- G-write (+bias): G[n][(row+n)%96] ----
#pragma unroll
        for (int j = 0; j < 3; ++j) {
            int n = (nt0 + j) * 16 + l15;
            float bn = biasL[n];
#pragma unroll
            for (int i = 0; i < 3; ++i) {
                int rbase = (mt0 + i) * 16 + quad * 4;
#pragma unroll
                for (int r = 0; r < 4; ++r) {
                    int rs = rbase + r + n; if (rs >= 96) rs -= 96;
                    G[n * 100 + rs] = acc[i][j][r] + bn;
                }
            }
        }
        __syncthreads();

        // ---- gate read/compute (+seq write) ----
        float ovv[5][2], hvv[5][2];
#pragma unroll
        for (int t = 0; t < 5; ++t) {
            int task = tid + t * TPB;
            if (task < 1152) {
                int row = rowT[t], dp = dpT[t];
#pragma unroll
                for (int dd = 0; dd < 2; ++dd) {
                    int d = 2 * dp + dd;
                    int n0 = d, n1 = 24 + d, n2 = 48 + d, n3 = 72 + d;
                    int r0 = row + n0; if (r0 >= 96) r0 -= 96;
                    int r1 = row + n1; if (r1 >= 96) r1 -= 96;
                    int r2 = row + n2; if (r2 >= 96) r2 -= 96;
                    int r3 = row + n3; if (r3 >= 96) r3 -= 96;
                    float gi = G[n0 * 100 + r0];
                    float gf = G[n1 * 100 + r1];
                    float gc = G[n2 * 100 + r2];
                    float go = G[n3 * 100 + r3];
                    float c = creg[t][dd];
                    float iv = sigm(fmaf(wgL[d], c, gi));
                    float fv = sigm(fmaf(wgL[24 + d], c, gf));
                    float cn = fmaf(fv, c, iv * tanh_(gc));
                    float ov = sigm(fmaf(wgL[48 + d], cn, go));
                    creg[t][dd] = cn;
                    ovv[t][dd] = ov;
                    hvv[t][dd] = ov * tanh_(cn);
                }
                if (s >= 24) {
                    long long off = seqbT[t] + (long long)(s - 24) * 576;
                    *(unsigned int*)(seqh + off) = pk2(ovv[t][0], ovv[t][1]);
                }
            }
        }
        __syncthreads();   // all G reads done before overlay writes

        // ---- gate write-back: UO operand planes + XH fp32 state ----
#pragma unroll
        for (int t = 0; t < 5; ++t) {
            int task = tid + t * TPB;
            if (task < 1152) {
                int row = rowT[t], dp = dpT[t];
                float o0 = ovv[t][0], o1 = ovv[t][1];
                float h0 = hvv[t][0], h1 = hvv[t][1];
                *(unsigned int*)(UO + row * 104 + 24 + 2 * dp) = pk2(o0, o1);
                *(unsigned int*)(UO + row * 104 + 72 + 2 * dp) = pk2(h0, h1);
                float* Q = XH + row * 50 + 2 * dp;
                Q[0] = o0; Q[1] = o1;
                Q[24] = h0; Q[25] = h1;
            }
        }
        __syncthreads();
    }
}

// Kernel 2: out[row][o] = bd[o] + sum_k seq[row][k]*Wd[o][k]; bf16 MFMA,
// single term (Wd-hi). 384 blocks x 256 thr, 128 rows/block, K chunks of 96.
extern "C" __global__ void __launch_bounds__(TPB)
gclstm_proj(const unsigned short* __restrict__ seqh,
            const float* __restrict__ Wd,
            const float* __restrict__ bd,
            float* __restrict__ out)
{
    __shared__ unsigned short SQ[128 * 104];   // 26,624 B
    __shared__ unsigned short WH[80 * 104];    // 16,640 B

    const int tid = threadIdx.x;
    const int R0 = blockIdx.x * 128;
    const int lane = tid & 63, wid = tid >> 6;
    const int l15 = lane & 15, quad = lane >> 4;

    f32x4 acc[2][5];
#pragma unroll
    for (int i = 0; i < 2; ++i)
#pragma unroll
        for (int j = 0; j < 5; ++j) acc[i][j] = (f32x4)0.f;

    for (int kc = 0; kc < 576; kc += 96) {
        __syncthreads();
        for (int i = tid; i < 1536; i += TPB) {          // 128 rows x 96 k, 16B chunks
            int r = i / 12, c8 = i - r * 12;
            *(s16x8*)(&SQ[r * 104 + c8 * 8]) =
                *(const s16x8*)(seqh + (size_t)(R0 + r) * 576 + (size_t)(kc + c8 * 8));
        }
        for (int i = tid; i < 7680; i += TPB) {          // 80 n-rows x 96 k
            int n = i / 96, kk = i - n * 96;
            float v = (n < 72) ? Wd[(size_t)n * 576 + (size_t)(kc + kk)] : 0.f;
            WH[n * 104 + kk] = f2b(v);
        }
        __syncthreads();
#pragma unroll
        for (int kt = 0; kt < 3; ++kt) {
            int koff = kt * 32 + quad * 8;
            s16x8 a[2], b[5];
#pragma unroll
            for (int i = 0; i < 2; ++i)
                a[i] = *(const s16x8*)(&SQ[((wid * 2 + i) * 16 + l15) * 104 + koff]);
#pragma unroll
            for (int j = 0; j < 5; ++j)
                b[j] = *(const s16x8*)(&WH[(j * 16 + l15) * 104 + koff]);
#pragma unroll
            for (int i = 0; i < 2; ++i)
#pragma unroll
                for (int j = 0; j < 5; ++j)
                    acc[i][j] = __builtin_amdgcn_mfma_f32_16x16x32_bf16(a[i], b[j], acc[i][j], 0, 0, 0);
        }
    }

#pragma unroll
    for (int j = 0; j < 5; ++j) {
        int n = j * 16 + l15;
        if (n < 72) {
            float bv = bd[n];
#pragma unroll
            for (int i = 0; i < 2; ++i) {
                int rbase = R0 + (wid * 2 + i) * 16 + quad * 4;
#pragma unroll
                for (int r = 0; r < 4; ++r)
                    out[(size_t)(rbase + r) * 72 + (size_t)n] = acc[i][j][r] + bv;
            }
        }
    }
}

extern "C" void kernel_launch(void* const* d_in, const int* in_sizes, int n_in,
                              void* d_out, int out_size, void* d_ws, size_t ws_size,
                              hipStream_t stream)
{
    const float* src = (const float*)d_in[0];
    const float* tgt = (const float*)d_in[1];
    const float* We  = (const float*)d_in[2];
    const float* be  = (const float*)d_in[3];
    const float* Wxl = (const float*)d_in[4];
    const float* bxl = (const float*)d_in[5];
    const float* Wxr = (const float*)d_in[6];
    const float* Whl = (const float*)d_in[7];
    const float* bhl = (const float*)d_in[8];
    const float* Whr = (const float*)d_in[9];
    const float* wg  = (const float*)d_in[10];
    const float* bg  = (const float*)d_in[11];
    const float* Wd  = (const float*)d_in[12];
    const float* bd  = (const float*)d_in[13];
    float* out = (float*)d_out;                     // [2048][24][72] fp32
    unsigned short* seqh = (unsigned short*)d_ws;   // [2048][24][576] bf16

    gclstm_main<<<dim3(512), dim3(TPB), 0, stream>>>(
        src, tgt, We, be, Wxl, bxl, Wxr, Whl, bhl, Whr, wg, bg, seqh);
    gclstm_proj<<<dim3(384), dim3(TPB), 0, stream>>>(seqh, Wd, bd, out);
}

// Round 7
// 395.089 us; speedup vs baseline: 4.8888x; 1.0745x over previous
//
#include <hip/hip_runtime.h>

// GC-LSTM (SMPL) — fp32 I/O. Round 7: occupancy restructure.
// Kernel 1: 1024 blocks x 192 thr (3 waves), NB=2 (48 rows), LDS 40,224 B ->
//   4 blocks/CU (12 waves). Per step: A-gather (fp32 XH) -> single-bf16 MFMA
//   (48x96x96, 18 tiles, 6/wave) -> G overlay (stride 49) -> fused gates
//   (c in regs) -> write-back. 5 barriers/step, stalls hidden by 4-deep blocks.
// Kernel 0: Wd -> bf16 preconvert into d_ws (if room; else proj converts inline).
// Kernel 2: projection, 64 rows/block, 5 blocks/CU.

typedef short s16x8 __attribute__((ext_vector_type(8)));
typedef float f32x4 __attribute__((ext_vector_type(4)));

#define TPB 192
#define NB 2
// kernel-1 LDS byte offsets (total 40,224 <= 40,960 for 4 blocks/CU)
#define UO_OFF   0        // ushort[48][104] = 9,984 : k 0-23 AX |24-47 X |48-71 Ah |72-95 h
#define XH_OFF   9984     // float [48][50]  = 9,600 : 0-23 X fp32 | 24-47 h fp32
#define G_OFF    0        // float [96][49]  = 18,816 : overlays UO+XH (phase-dead)
#define W_OFF    19584    // ushort[96][104] = 19,968 : W[n][k] bf16
#define BIAS_OFF 39552    // float[96]
#define WG_OFF   39936    // float[72]
#define SMEM_SZ  40224

__device__ __forceinline__ float b2f(unsigned short u) {
    return __uint_as_float(((unsigned int)u) << 16);
}
__device__ __forceinline__ unsigned short f2b(float f) {
    unsigned int x = __float_as_uint(f);
    x = x + 0x7fffu + ((x >> 16) & 1u);   // RNE
    return (unsigned short)(x >> 16);
}
__device__ __forceinline__ unsigned int pk2(float a, float b) {
    return (unsigned int)f2b(a) | ((unsigned int)f2b(b) << 16);
}
__device__ __forceinline__ float frcp(float x) { return __builtin_amdgcn_rcpf(x); }
__device__ __forceinline__ float sigm(float x) {
    float t = __expf(-x);
    return frcp(1.0f + t);
}
__device__ __forceinline__ float tanh_(float x) {
    float xc = fmaxf(x, -30.f);
    float t = __expf(-2.f * xc);
    return (1.f - t) * frcp(1.f + t);
}

extern "C" __global__ void __launch_bounds__(TPB, 3)
gclstm_main(const float* __restrict__ src,
            const float* __restrict__ tgt,
            const float* __restrict__ We,
            const float* __restrict__ be,
            const float* __restrict__ Wxl,
            const float* __restrict__ bxl,
            const float* __restrict__ Wxr,
            const float* __restrict__ Whl,
            const float* __restrict__ bhl,
            const float* __restrict__ Whr,
            const float* __restrict__ wg,
            const float* __restrict__ bg,
            unsigned short* __restrict__ seqh)
{
    __shared__ __align__(16) char smem[SMEM_SZ];
    unsigned short* UO = (unsigned short*)(smem + UO_OFF);
    float* XH = (float*)(smem + XH_OFF);
    float* G  = (float*)(smem + G_OFF);
    unsigned short* WO = (unsigned short*)(smem + W_OFF);
    float* biasL = (float*)(smem + BIAS_OFF);
    float* wgL = (float*)(smem + WG_OFF);

    const int tid = threadIdx.x;
    const int b0 = blockIdx.x * NB;
    const int lane = tid & 63, wid = tid >> 6;      // 3 waves
    const int l15 = lane & 15, quad = lane >> 4;

    // ---- stage W[n][k] bf16; k pairs U planes: 0-23 Wxl |24-47 Wxr |48-71 Whl |72-95 Whr
    for (int i = tid; i < 9216; i += TPB) {
        int n = i / 96, k = i - n * 96;
        int g = n / 24, d = n - g * 24;
        int e = k % 24, sel = k / 24;
        const float* w = sel == 0 ? Wxl : sel == 1 ? Wxr : sel == 2 ? Whl : Whr;
        WO[n * 104 + k] = f2b(w[g * 576 + d * 24 + e]);
    }
    if (tid < 96) biasL[tid] = bxl[tid] + bhl[tid] + bg[tid];
    if (tid < 72) wgL[tid] = wg[tid];

    // ---- per-thread task constants: task = row*12 + dp, 576 tasks = 3/thread exact
    int rowT[3], dpT[3], rbT[3];
    unsigned int ncodeT[3];
    long long seqbT[3];
    {
        const int par[24] = {-1,0,0,0,1,2,3,4,5,6,7,8,9,9,9,12,13,14,16,17,18,19,20,21};
#pragma unroll
        for (int t = 0; t < 3; ++t) {
            int task = tid + t * TPB;
            int row = task / 12, dp = task - row * 12;
            int j = row % 24;
            rowT[t] = row; dpT[t] = dp; rbT[t] = row - j;
            int arr[5]; int cnt = 0;
            arr[cnt++] = j;
            if (par[j] >= 0) arr[cnt++] = par[j];
#pragma unroll
            for (int ch = 0; ch < 24; ++ch)
                if (par[ch] == j && cnt < 5) arr[cnt++] = ch;
            for (int m = cnt; m < 5; ++m) arr[m] = j;  // self-pad
            ncodeT[t] = (unsigned int)arr[0] | ((unsigned int)arr[1] << 5)
                      | ((unsigned int)arr[2] << 10) | ((unsigned int)arr[3] << 15)
                      | ((unsigned int)arr[4] << 20) | ((unsigned int)cnt << 25);
            seqbT[t] = (long long)(b0 + row / 24) * 24 * 576 + (long long)j * 24 + 2 * dp;
        }
    }

    float creg[3][2];
#pragma unroll
    for (int t = 0; t < 3; ++t) { creg[t][0] = 0.f; creg[t][1] = 0.f; }

    // ---- encoder init: X0 = relu(enc(src[:,0])), h = 0 ----
#pragma unroll
    for (int t = 0; t < 3; ++t) {
        int row = rowT[t], dp = dpT[t];
        int b = b0 + row / 24, j = row % 24;
        const float* sp = src + (size_t)b * 1728 + j * 3;
        float s0 = sp[0], s1 = sp[1], s2 = sp[2];
        int d = 2 * dp;
        float x0 = be[d] + s0 * We[d * 3] + s1 * We[d * 3 + 1] + s2 * We[d * 3 + 2];
        float x1 = be[d + 1] + s0 * We[d * 3 + 3] + s1 * We[d * 3 + 4] + s2 * We[d * 3 + 5];
        x0 = fmaxf(x0, 0.f); x1 = fmaxf(x1, 0.f);
        *(unsigned int*)(UO + row * 104 + 24 + d) = pk2(x0, x1);
        *(unsigned int*)(UO + row * 104 + 72 + d) = 0u;
        XH[row * 50 + d] = x0; XH[row * 50 + d + 1] = x1;
        XH[row * 50 + 24 + d] = 0.f; XH[row * 50 + 24 + d + 1] = 0.f;
    }
    __syncthreads();

    for (int s = 0; s < 48; ++s) {
        if (s == 24) {
            // decode inject: X = relu(enc(tgt[:,0])), h/c carried
#pragma unroll
            for (int t = 0; t < 3; ++t) {
                int row = rowT[t], dp = dpT[t];
                int b = b0 + row / 24, j = row % 24;
                const float* tp = tgt + (size_t)b * 1728 + j * 3;
                float s0 = tp[0], s1 = tp[1], s2 = tp[2];
                int d = 2 * dp;
                float x0 = be[d] + s0 * We[d * 3] + s1 * We[d * 3 + 1] + s2 * We[d * 3 + 2];
                float x1 = be[d + 1] + s0 * We[d * 3 + 3] + s1 * We[d * 3 + 4]
                         + s2 * We[d * 3 + 5];
                x0 = fmaxf(x0, 0.f); x1 = fmaxf(x1, 0.f);
                *(unsigned int*)(UO + row * 104 + 24 + d) = pk2(x0, x1);
                XH[row * 50 + d] = x0; XH[row * 50 + d + 1] = x1;
            }
            __syncthreads();
        }

        // ---- A-phase: gather fp32 XH -> bf16 AX,Ah planes of UO ----
#pragma unroll
        for (int t = 0; t < 3; ++t) {
            int row = rowT[t], dp = dpT[t], rb = rbT[t];
            unsigned int nc = ncodeT[t];
            int cnt = (int)(nc >> 25);
            float sx0 = 0.f, sx1 = 0.f, sh0 = 0.f, sh1 = 0.f;
            float fx0 = 0.f, fx1 = 0.f, fh0 = 0.f, fh1 = 0.f;
#pragma unroll
            for (int m = 0; m < 5; ++m) {
                int nb = (int)((nc >> (5 * m)) & 31u);
                const float* P = XH + (rb + nb) * 50 + 2 * dp;
                float vx0 = P[0], vx1 = P[1];
                float vh0 = P[24], vh1 = P[25];
                sx0 += vx0; sx1 += vx1; sh0 += vh0; sh1 += vh1;
                if (m == 0) { fx0 = vx0; fx1 = vx1; fh0 = vh0; fh1 = vh1; }
            }
            float corr = (float)(5 - cnt);
            float iw = cnt == 2 ? 0.5f : cnt == 3 ? (1.f / 3.f)
                     : cnt == 4 ? 0.25f : 0.2f;
            *(unsigned int*)(UO + row * 104 + 2 * dp) =
                pk2((sx0 - corr * fx0) * iw, (sx1 - corr * fx1) * iw);
            *(unsigned int*)(UO + row * 104 + 48 + 2 * dp) =
                pk2((sh0 - corr * fh0) * iw, (sh1 - corr * fh1) * iw);
        }
        __syncthreads();   // (1)

        // ---- GEMM: G[row][n] = sum_k U[row][k]*W[n][k]; wave owns n-tiles {2w,2w+1}
        f32x4 acc[3][2];
#pragma unroll
        for (int i = 0; i < 3; ++i)
#pragma unroll
            for (int j = 0; j < 2; ++j) acc[i][j] = (f32x4)0.f;
#pragma unroll
        for (int kt = 0; kt < 3; ++kt) {
            int koff = kt * 32 + quad * 8;
            s16x8 a[3], b[2];
#pragma unroll
            for (int i = 0; i < 3; ++i)
                a[i] = *(const s16x8*)(UO + (i * 16 + l15) * 104 + koff);
#pragma unroll
            for (int j = 0; j < 2; ++j)
                b[j] = *(const s16x8*)(WO + ((2 * wid + j) * 16 + l15) * 104 + koff);
#pragma unroll
            for (int i = 0; i < 3; ++i)
#pragma unroll
                for (int j = 0; j < 2; ++j)
                    acc[i][j] = __builtin_amdgcn_mfma_f32_16x16x32_bf16(a[i], b[j], acc[i][j], 0, 0, 0);
        }
        __syncthreads();   // (2) UO reads done before G overlay

        // ---- G-write (+bias): G[n*49 + (row+n)%48] ----
#pragma unroll
        for (int j = 0; j < 2; ++j) {
            int n = (2 * wid + j) * 16 + l15;
            float bn = biasL[n];
            int nm = n; if (nm >= 48) nm -= 48;
#pragma unroll
            for (int i = 0; i < 3; ++i) {
                int rs0 = i * 16 + quad * 4 + nm;
#pragma unroll
                for (int r = 0; r < 4; ++r) {
                    int rs = rs0 + r; if (rs >= 48) rs -= 48;
                    G[n * 49 + rs] = acc[i][j][r] + bn;
                }
            }
        }
        __syncthreads();   // (3)

        // ---- gate phase: read G, compute, write seq ----
        float ovv[3][2], hvv[3][2];
#pragma unroll
        for (int t = 0; t < 3; ++t) {
            int row = rowT[t], dp = dpT[t];
#pragma unroll
            for (int dd = 0; dd < 2; ++dd) {
                int d = 2 * dp + dd;
                int ra = row + d;      if (ra >= 48) ra -= 48;
                int rb2 = row + 24 + d; if (rb2 >= 48) rb2 -= 48;
                float gi = G[d * 49 + ra];
                float gf = G[(24 + d) * 49 + rb2];
                float gc = G[(48 + d) * 49 + ra];
                float go = G[(72 + d) * 49 + rb2];
                float c = creg[t][dd];
                float iv = sigm(fmaf(wgL[d], c, gi));
                float fv = sigm(fmaf(wgL[24 + d], c, gf));
                float cn = fmaf(fv, c, iv * tanh_(gc));
                float ov = sigm(fmaf(wgL[48 + d], cn, go));
                creg[t][dd] = cn;
                ovv[t][dd] = ov;
                hvv[t][dd] = ov * tanh_(cn);
            }
            if (s >= 24) {
                long long off = seqbT[t] + (long long)(s - 24) * 576;
                *(unsigned int*)(seqh + off) = pk2(ovv[t][0], ovv[t][1]);
            }
        }
        __syncthreads();   // (4) G reads done before overlay overwrite

        // ---- write-back: UO operand planes + XH fp32 state ----
#pragma unroll
        for (int t = 0; t < 3; ++t) {
            int row = rowT[t], dp = dpT[t];
            float o0 = ovv[t][0], o1 = ovv[t][1];
            float h0 = hvv[t][0], h1 = hvv[t][1];
            *(unsigned int*)(UO + row * 104 + 24 + 2 * dp) = pk2(o0, o1);
            *(unsigned int*)(UO + row * 104 + 72 + 2 * dp) = pk2(h0, h1);
            float* Q = XH + row * 50 + 2 * dp;
            Q[0] = o0; Q[1] = o1;
            Q[24] = h0; Q[25] = h1;
        }
        __syncthreads();   // (5)
    }
}

// Kernel 0: Wd (72x576 fp32) -> WdH (80x576 bf16, rows 72-79 zero)
extern "C" __global__ void __launch_bounds__(256)
wd_conv(const float* __restrict__ Wd, unsigned short* __restrict__ WdH)
{
    int i = blockIdx.x * 256 + threadIdx.x;
    if (i < 46080) {
        int n = i / 576, k = i - n * 576;
        WdH[i] = (n < 72) ? f2b(Wd[n * 576 + k]) : (unsigned short)0;
    }
}

// Kernel 2: out[row][o] = bd[o] + sum_k seq[row][k]*Wd[o][k]; bf16 MFMA.
// 768 blocks x 256 thr, 64 rows/block (wave w owns m-tile w), K chunks of 96.
// LDS: SQ 64x104 shorts = 13,312; WH 80x104 shorts = 16,640 -> 29,952 B (5 blk/CU)
template <int PRECONV>
__global__ void __launch_bounds__(256, 4)
gclstm_proj(const unsigned short* __restrict__ seqh,
            const unsigned short* __restrict__ WdH,
            const float* __restrict__ Wd,
            const float* __restrict__ bd,
            float* __restrict__ out)
{
    __shared__ unsigned short SQ[64 * 104];
    __shared__ unsigned short WH[80 * 104];

    const int tid = threadIdx.x;
    const int R0 = blockIdx.x * 64;
    const int lane = tid & 63, wid = tid >> 6;
    const int l15 = lane & 15, quad = lane >> 4;

    f32x4 acc[5];
#pragma unroll
    for (int j = 0; j < 5; ++j) acc[j] = (f32x4)0.f;

    for (int kc = 0; kc < 576; kc += 96) {
        __syncthreads();
        for (int i = tid; i < 768; i += 256) {           // 64 rows x 12 b128-chunks
            int r = i / 12, c8 = i - r * 12;
            *(s16x8*)(&SQ[r * 104 + c8 * 8]) =
                *(const s16x8*)(seqh + (size_t)(R0 + r) * 576 + (size_t)(kc + c8 * 8));
        }
        if (PRECONV) {
            for (int i = tid; i < 960; i += 256) {       // 80 n x 12 b128-chunks
                int n = i / 12, c8 = i - n * 12;
                *(s16x8*)(&WH[n * 104 + c8 * 8]) =
                    *(const s16x8*)(WdH + (size_t)n * 576 + (size_t)(kc + c8 * 8));
            }
        } else {
            for (int i = tid; i < 7680; i += 256) {
                int n = i / 96, kk = i - n * 96;
                float v = (n < 72) ? Wd[(size_t)n * 576 + (size_t)(kc + kk)] : 0.f;
                WH[n * 104 + kk] = f2b(v);
            }
        }
        __syncthreads();
#pragma unroll
        for (int kt = 0; kt < 3; ++kt) {
            int koff = kt * 32 + quad * 8;
            s16x8 a = *(const s16x8*)(&SQ[(wid * 16 + l15) * 104 + koff]);
#pragma unroll
            for (int j = 0; j < 5; ++j) {
                s16x8 b = *(const s16x8*)(&WH[(j * 16 + l15) * 104 + koff]);
                acc[j] = __builtin_amdgcn_mfma_f32_16x16x32_bf16(a, b, acc[j], 0, 0, 0);
            }
        }
    }

#pragma unroll
    for (int j = 0; j < 5; ++j) {
        int n = j * 16 + l15;
        if (n < 72) {
            float bv = bd[n];
            int rbase = R0 + wid * 16 + quad * 4;
#pragma unroll
            for (int r = 0; r < 4; ++r)
                out[(size_t)(rbase + r) * 72 + (size_t)n] = acc[j][r] + bv;
        }
    }
}

extern "C" void kernel_launch(void* const* d_in, const int* in_sizes, int n_in,
                              void* d_out, int out_size, void* d_ws, size_t ws_size,
                              hipStream_t stream)
{
    const float* src = (const float*)d_in[0];
    const float* tgt = (const float*)d_in[1];
    const float* We  = (const float*)d_in[2];
    const float* be  = (const float*)d_in[3];
    const float* Wxl = (const float*)d_in[4];
    const float* bxl = (const float*)d_in[5];
    const float* Wxr = (const float*)d_in[6];
    const float* Whl = (const float*)d_in[7];
    const float* bhl = (const float*)d_in[8];
    const float* Whr = (const float*)d_in[9];
    const float* wg  = (const float*)d_in[10];
    const float* bg  = (const float*)d_in[11];
    const float* Wd  = (const float*)d_in[12];
    const float* bd  = (const float*)d_in[13];
    float* out = (float*)d_out;                     // [2048][24][72] fp32
    unsigned short* seqh = (unsigned short*)d_ws;   // [2048][24][576] bf16 = 56,623,104 B

    const size_t seq_bytes = (size_t)2048 * 24 * 576 * 2;
    unsigned short* WdH = (unsigned short*)((char*)d_ws + seq_bytes);
    const bool preconv = ws_size >= seq_bytes + (size_t)80 * 576 * 2;

    if (preconv)
        wd_conv<<<dim3(180), dim3(256), 0, stream>>>(Wd, WdH);
    gclstm_main<<<dim3(1024), dim3(TPB), 0, stream>>>(
        src, tgt, We, be, Wxl, bxl, Wxr, Whl, bhl, Whr, wg, bg, seqh);
    if (preconv)
        gclstm_proj<1><<<dim3(768), dim3(256), 0, stream>>>(seqh, WdH, Wd, bd, out);
    else
        gclstm_proj<0><<<dim3(768), dim3(256), 0, stream>>>(seqh, nullptr, Wd, bd, out);
}